// Round 1
// baseline (89.535 us; speedup 1.0000x reference)
//
#include <hip/hip_runtime.h>
#include <math.h>

#define TOKENS (16*2048)
#define T_SEQ 2048
#define NVOC 42

// ws layout (floats)
#define OFF_UE  0        // 42*64
#define OFF_RE  2688     // 42*64
#define OFF_VE  5376     // 43*128
#define OFF_TAU 10880    // 42*43
#define OFF_VM  12686    // 43*128
#define OFF_YA  18190    // 42*128

// K1: ue/re (per-id w1 halves), ve (per-id value vectors incl. pad row), ya (x@mg_w[:128]+mg_b)
__global__ __launch_bounds__(128) void k_pre1(const float* __restrict__ emb,
    const float* __restrict__ w1, const float* __restrict__ b1,
    const float* __restrict__ wv_w, const float* __restrict__ wv_b,
    const float* __restrict__ mg_w, const float* __restrict__ mg_b,
    float* __restrict__ ws){
  int blk = blockIdx.x, tid = threadIdx.x;
  if (blk < 42){
    if (tid < 64){
      float su = b1[tid], sr = 0.f;
      for (int i = 0; i < 128; ++i){
        float e = emb[blk*128 + i];
        su = fmaf(e, w1[i*64 + tid], su);
        sr = fmaf(e, w1[(128+i)*64 + tid], sr);
      }
      ws[OFF_UE + blk*64 + tid] = su;
      ws[OFF_RE + blk*64 + tid] = sr;
    }
  } else if (blk < 85){
    int c = blk - 42;                 // 0..42 (42 == zero-padded neighbor)
    float s = wv_b[tid];
    if (c < 42){
      for (int i = 0; i < 128; ++i) s = fmaf(emb[c*128 + i], wv_w[i*128 + tid], s);
    }
    ws[OFF_VE + c*128 + tid] = s;
  } else {
    int a = blk - 85;                 // 0..41
    float s = mg_b[tid];
    for (int i = 0; i < 128; ++i) s = fmaf(emb[a*128 + i], mg_w[i*128 + tid], s);
    ws[OFF_YA + a*128 + tid] = s;
  }
}

// K2: tau table (42x43) and vm = ve @ mg_w[128:] (43x128)
__global__ __launch_bounds__(128) void k_pre2(const float* __restrict__ w2,
    const float* __restrict__ b2, const float* __restrict__ mg_w,
    float* __restrict__ ws){
  int blk = blockIdx.x, tid = threadIdx.x;
  if (blk < 42){
    if (tid < 43){
      float s = b2[0];
      for (int k = 0; k < 64; ++k){
        float h = ws[OFF_UE + blk*64 + k] + (tid < 42 ? ws[OFF_RE + tid*64 + k] : 0.f);
        float sg = 1.f/(1.f + __expf(-h));     // sigmoid
        s = fmaf(h*sg, w2[k], s);              // silu(h)*w2
      }
      ws[OFF_TAU + blk*43 + tid] = 1.f/(1.f + __expf(-s));
    }
  } else {
    int c = blk - 42;                 // 0..42
    float s = 0.f;
    for (int i = 0; i < 128; ++i) s = fmaf(ws[OFF_VE + c*128 + i], mg_w[(128+i)*128 + tid], s);
    ws[OFF_VM + c*128 + tid] = s;
  }
}

// K3: per token: y = ya[a] + sum_w tau[a,c_w]*vm[c_w]; LN; out = scale*(y@head_w)+head_b
__global__ __launch_bounds__(256) void k_main(const int* __restrict__ ids,
    const float* __restrict__ ln_g, const float* __restrict__ ln_b,
    const float* __restrict__ head_w, const float* __restrict__ head_b,
    const float* __restrict__ ws, float* __restrict__ out){
  __shared__ float s_tau[42*43];
  __shared__ float s_vm[43*128];
  __shared__ float s_hw[128*42];
  __shared__ float s_y[2][128];
  __shared__ float s_hp[2][3][42];
  __shared__ float s_red[4][2];
  __shared__ int   s_id[2][17];
  int tid = threadIdx.x;
  for (int i = tid; i < 42*43;  i += 256) s_tau[i] = ws[OFF_TAU + i];
  for (int i = tid; i < 43*128; i += 256) s_vm[i]  = ws[OFF_VM + i];
  for (int i = tid; i < 128*42; i += 256) s_hw[i]  = head_w[i];
  int slot = tid >> 7, j = tid & 127, wv = tid >> 6;
  float lng = ln_g[j], lnb = ln_b[j];
  float hb  = (j < 42) ? head_b[j] : 0.f;
  const float omega = 0.52359877559829887f;     // 2*pi/12
  const float phase = 2048.f * omega;           // Tlen*omega
  __syncthreads();

  int base = blockIdx.x * 32;                   // 1024 blocks * 32 tokens = 32768
  for (int it = 0; it < 32; it += 2){
    int tok = base + it + slot;
    int btt = tok & (T_SEQ - 1);                // position within sequence
    if (j < 17){
      int v;
      if (j == 16) v = ids[tok];
      else { int idx = btt - j - 1; v = (idx >= 0) ? ids[tok - j - 1] : NVOC; }
      s_id[slot][j] = v;
    }
    __syncthreads();

    int a = s_id[slot][16];
    float acc = ws[OFF_YA + a*128 + j];
    #pragma unroll
    for (int w = 0; w < 16; ++w){
      int c = s_id[slot][w];
      acc = fmaf(s_tau[a*43 + c], s_vm[c*128 + j], acc);
    }

    // LayerNorm: reduce sum and sumsq over the 128 threads of this slot
    float s1 = acc, s2 = acc*acc;
    #pragma unroll
    for (int off = 32; off; off >>= 1){ s1 += __shfl_xor(s1, off); s2 += __shfl_xor(s2, off); }
    if ((tid & 63) == 0){ s_red[wv][0] = s1; s_red[wv][1] = s2; }
    __syncthreads();
    float sum = s_red[slot*2][0] + s_red[slot*2+1][0];
    float sq  = s_red[slot*2][1] + s_red[slot*2+1][1];
    float mu  = sum * (1.f/128.f);
    float var = sq  * (1.f/128.f) - mu*mu;
    float rinv = rsqrtf(var + 1e-5f);
    s_y[slot][j] = (acc - mu)*rinv*lng + lnb;
    __syncthreads();

    // head: 3-way split of the 128-dim dot across 126 lanes
    if (j < 126){
      int part = j/42, o = j - part*42;
      int i0 = part*44, i1 = (part == 2) ? 128 : (i0 + 44);
      float d0 = 0.f, d1 = 0.f;
      for (int i = i0; i < i1; i += 2){
        d0 = fmaf(s_y[slot][i],   s_hw[i*42 + o],     d0);
        d1 = fmaf(s_y[slot][i+1], s_hw[(i+1)*42 + o], d1);
      }
      s_hp[slot][part][o] = d0 + d1;
    }
    __syncthreads();
    if (j < 42){
      float dot = s_hp[slot][0][j] + s_hp[slot][1][j] + s_hp[slot][2][j];
      float scale = 1.f + 0.15f*sinf((float)btt*omega + phase);
      out[tok*42 + j] = fmaf(scale, dot, hb);
    }
  }
}

extern "C" void kernel_launch(void* const* d_in, const int* in_sizes, int n_in,
                              void* d_out, int out_size, void* d_ws, size_t ws_size,
                              hipStream_t stream){
  const int*   ids    = (const int*)  d_in[0];
  const float* emb    = (const float*)d_in[1];
  const float* w1     = (const float*)d_in[2];
  const float* b1     = (const float*)d_in[3];
  const float* w2     = (const float*)d_in[4];
  const float* b2     = (const float*)d_in[5];
  const float* wv_w   = (const float*)d_in[6];
  const float* wv_b   = (const float*)d_in[7];
  const float* mg_w   = (const float*)d_in[8];
  const float* mg_b   = (const float*)d_in[9];
  const float* ln_g   = (const float*)d_in[10];
  const float* ln_b   = (const float*)d_in[11];
  const float* head_w = (const float*)d_in[12];
  const float* head_b = (const float*)d_in[13];
  float* ws  = (float*)d_ws;
  float* out = (float*)d_out;
  k_pre1<<<dim3(127),  dim3(128), 0, stream>>>(emb, w1, b1, wv_w, wv_b, mg_w, mg_b, ws);
  k_pre2<<<dim3(85),   dim3(128), 0, stream>>>(w2, b2, mg_w, ws);
  k_main<<<dim3(1024), dim3(256), 0, stream>>>(ids, ln_g, ln_b, head_w, head_b, ws, out);
}

// Round 2
// 30.301 us; speedup vs baseline: 2.9548x; 2.9548x over previous
//
#include <hip/hip_runtime.h>
#include <hip/hip_bf16.h>
#include <math.h>

typedef __attribute__((ext_vector_type(8))) short short8;
typedef __attribute__((ext_vector_type(4))) float f32x4;

#define T_SEQ 2048
#define NVOC 42

// ws float offsets
#define OFF_UE  0        // 42*64
#define OFF_RE  2688     // 42*64
#define OFF_VE  5376     // 43*128 -> 10880
#define OFF_TAU 10880    // 42*43 = 1806 -> 12686
#define OFF_VM  12686    // 43*128 -> 18190
#define OFF_YA  18190    // 42*128 -> 23566
#define OFF_WB  23568    // ushort region: 12288 u16 (8n x 16col x 96k bf16) -> +6144 floats
#define OFF_HB  29712    // ushort region: 6144 u16 (12 frag x 64 lane x 8 bf16)

static __device__ __forceinline__ short f2b(float x){
  __hip_bfloat16 h = __float2bfloat16(x);
  return *reinterpret_cast<short*>(&h);
}

// K1: ue/re (w1 halves per id), ve (43 value vectors incl pad), ya (x@mg_w[:128]+mg_b)
__global__ __launch_bounds__(128) void k_pre1(const float* __restrict__ emb,
    const float* __restrict__ w1, const float* __restrict__ b1,
    const float* __restrict__ wv_w, const float* __restrict__ wv_b,
    const float* __restrict__ mg_w, const float* __restrict__ mg_b,
    float* __restrict__ ws){
  int blk = blockIdx.x, tid = threadIdx.x;
  if (blk < 42){
    if (tid < 64){
      float su = b1[tid], sr = 0.f;
      for (int i = 0; i < 128; ++i){
        float e = emb[blk*128 + i];
        su = fmaf(e, w1[i*64 + tid], su);
        sr = fmaf(e, w1[(128+i)*64 + tid], sr);
      }
      ws[OFF_UE + blk*64 + tid] = su;
      ws[OFF_RE + blk*64 + tid] = sr;
    }
  } else if (blk < 85){
    int c = blk - 42;                 // 0..42 (42 == zero-padded neighbor)
    float s = wv_b[tid];
    if (c < 42){
      for (int i = 0; i < 128; ++i) s = fmaf(emb[c*128 + i], wv_w[i*128 + tid], s);
    }
    ws[OFF_VE + c*128 + tid] = s;
  } else {
    int a = blk - 85;                 // 0..41
    float s = mg_b[tid];
    for (int i = 0; i < 128; ++i) s = fmaf(emb[a*128 + i], mg_w[i*128 + tid], s);
    ws[OFF_YA + a*128 + tid] = s;
  }
}

// K2: tau table (42x43) and vm = ve @ mg_w[128:] (43x128)
__global__ __launch_bounds__(128) void k_pre2(const float* __restrict__ w2,
    const float* __restrict__ b2, const float* __restrict__ mg_w,
    float* __restrict__ ws){
  int blk = blockIdx.x, tid = threadIdx.x;
  if (blk < 42){
    if (tid < 43){
      float s = b2[0];
      for (int k = 0; k < 64; ++k){
        float h = ws[OFF_UE + blk*64 + k] + (tid < 42 ? ws[OFF_RE + tid*64 + k] : 0.f);
        float sg = 1.f/(1.f + __expf(-h));
        s = fmaf(h*sg, w2[k], s);
      }
      ws[OFF_TAU + blk*43 + tid] = 1.f/(1.f + __expf(-s));
    }
  } else {
    int c = blk - 42;
    float s = 0.f;
    for (int i = 0; i < 128; ++i) s = fmaf(ws[OFF_VE + c*128 + i], mg_w[(128+i)*128 + tid], s);
    ws[OFF_VM + c*128 + tid] = s;
  }
}

// K3: gather W table (vm rows 0..42, ya rows 43..84, zero 85..95) into bf16 B-layout
//     [n(8)][col(16)][k(96)], and head_w into per-lane B-frags [12][64][8] bf16.
__global__ __launch_bounds__(256) void k_pre3(const float* __restrict__ head_w,
    float* __restrict__ ws){
  int idx = blockIdx.x*256 + threadIdx.x;
  ushort* wb  = (ushort*)(ws + OFF_WB);
  ushort* hbt = (ushort*)(ws + OFF_HB);
  if (idx < 12288){
    int n = idx / 1536, rem = idx % 1536, col = rem / 96, k = rem % 96;
    int d = n*16 + col;
    float v = 0.f;
    if (k < 43)      v = ws[OFF_VM + k*128 + d];
    else if (k < 85) v = ws[OFF_YA + (k-43)*128 + d];
    wb[idx] = (ushort)f2b(v);
  } else if (idx < 18432){
    int i2 = idx - 12288;
    int f = i2 >> 9;                  // 0..11 : (n2*4 + c)
    int ln = (i2 >> 3) & 63, j = i2 & 7;
    int n2 = f >> 2, c = f & 3;
    int k = c*32 + (ln>>4)*8 + j;
    int col = n2*16 + (ln & 15);
    float v = (col < NVOC) ? head_w[k*NVOC + col] : 0.f;
    hbt[i2] = (ushort)f2b(v);
  }
}

// K4: per wave: 16 tokens. Build T (96-slot) via LDS atomics, msg+ya via MFMA vs W,
// LN via shuffles, head via MFMA vs resident head-frags. No barriers in main phase.
__global__ __launch_bounds__(256) void k_main(const int* __restrict__ ids,
    const float* __restrict__ ln_g, const float* __restrict__ ln_b,
    const float* __restrict__ head_b, const float* __restrict__ ws,
    float* __restrict__ out){
  __shared__ __align__(16) float  s_tau[1808];
  __shared__ __align__(16) ushort s_wb[12288];
  __shared__ __align__(16) float  s_T[4][1600];   // per-wave: T[16][100] f32, later Y[16][136] bf16
  __shared__ int s_ids[4][32];

  int tid = threadIdx.x, wv = tid >> 6, lane = tid & 63;
  int r = lane & 15, q = lane >> 4;
  int base = blockIdx.x*64 + wv*16;

  // block-wide staging of tables
  {
    const float4* src = (const float4*)(ws + OFF_TAU);
    float4* dst = (float4*)s_tau;
    for (int i = tid; i < 452; i += 256) dst[i] = src[i];
    const float4* s2 = (const float4*)(ws + OFF_WB);
    float4* d2 = (float4*)s_wb;
    for (int i = tid; i < 1536; i += 256) d2[i] = s2[i];
  }
  if (lane < 32){
    int v;
    if ((base & (T_SEQ-1)) == 0 && lane < 16) v = NVOC;   // pad ids before sequence start
    else v = ids[base - 16 + lane];
    s_ids[wv][lane] = v;
  }
  // resident head B-frags + per-lane LN params + head bias
  short8 HBf[3][4];
  {
    const ushort* hbsrc = (const ushort*)(ws + OFF_HB);
    #pragma unroll
    for (int n2 = 0; n2 < 3; ++n2)
      #pragma unroll
      for (int c = 0; c < 4; ++c)
        HBf[n2][c] = *(const short8*)&hbsrc[((n2*4 + c)*64 + lane)*8];
  }
  float gd[8], bd[8];
  #pragma unroll
  for (int n = 0; n < 8; ++n){ gd[n] = ln_g[n*16 + r]; bd[n] = ln_b[n*16 + r]; }
  float hb[3];
  #pragma unroll
  for (int n2 = 0; n2 < 3; ++n2){ int col = n2*16 + r; hb[n2] = (col < NVOC) ? head_b[col] : 0.f; }
  __syncthreads();

  float* T = s_T[wv];
  // zero T region (16*100 f32)
  {
    float4 z; z.x = z.y = z.z = z.w = 0.f;
    float4* t4 = (float4*)T;
    for (int i = lane; i < 400; i += 64) t4[i] = z;
  }
  int a = s_ids[wv][16 + r];
  #pragma unroll
  for (int m = 0; m < 4; ++m){
    int w = q*4 + m;
    int c = s_ids[wv][r + 15 - w];
    float tv = s_tau[a*43 + c];
    atomicAdd(&T[r*100 + c], tv);        // ds_add_f32
  }
  if (q == 0) T[r*100 + 43 + a] = 1.0f;  // selects ya row
  __asm__ volatile("s_waitcnt lgkmcnt(0)" ::: "memory");

  // msg+ya MFMA: y[16 tok x 128 d] = T[16x96] @ W[96x128]
  f32x4 accm[8];
  #pragma unroll
  for (int n = 0; n < 8; ++n){ accm[n][0]=0.f; accm[n][1]=0.f; accm[n][2]=0.f; accm[n][3]=0.f; }
  short8 A1[3];
  #pragma unroll
  for (int ct = 0; ct < 3; ++ct){
    const float4* p = (const float4*)&T[r*100 + ct*32 + q*8];
    float4 u0 = p[0], u1 = p[1];
    short8 v;
    v[0]=f2b(u0.x); v[1]=f2b(u0.y); v[2]=f2b(u0.z); v[3]=f2b(u0.w);
    v[4]=f2b(u1.x); v[5]=f2b(u1.y); v[6]=f2b(u1.z); v[7]=f2b(u1.w);
    A1[ct] = v;
  }
  #pragma unroll
  for (int ct = 0; ct < 3; ++ct){
    #pragma unroll
    for (int n = 0; n < 8; ++n){
      short8 b = *(const short8*)&s_wb[n*1536 + r*96 + ct*32 + q*8];
      accm[n] = __builtin_amdgcn_mfma_f32_16x16x32_bf16(A1[ct], b, accm[n], 0, 0, 0);
    }
  }

  // LN + scale + bf16 to LDS (overlay on T): lane holds y[tok=4q+reg][d=n*16+r]
  ushort* sY = (ushort*)T;               // Y[16][136] bf16
  #pragma unroll
  for (int reg = 0; reg < 4; ++reg){
    float s1 = 0.f, s2 = 0.f;
    #pragma unroll
    for (int n = 0; n < 8; ++n){ float y = accm[n][reg]; s1 += y; s2 = fmaf(y, y, s2); }
    #pragma unroll
    for (int mk = 1; mk < 16; mk <<= 1){ s1 += __shfl_xor(s1, mk); s2 += __shfl_xor(s2, mk); }
    float mu  = s1 * (1.f/128.f);
    float var = s2 * (1.f/128.f) - mu*mu;
    float rinv = rsqrtf(var + 1e-5f);
    int tok = base + q*4 + reg;
    int m12 = ((tok & (T_SEQ-1)) + 8) % 12;     // (btt + 2048) mod 12
    float sc = fmaf(0.15f, __sinf((float)m12 * 0.52359877559829887f), 1.0f);
    float A_ = rinv * sc;
    #pragma unroll
    for (int n = 0; n < 8; ++n){
      float yl = (accm[n][reg] - mu) * A_;
      float o  = fmaf(yl, gd[n], bd[n]*sc);
      sY[(q*4 + reg)*136 + n*16 + r] = (ushort)f2b(o);
    }
  }

  // head MFMA: out[16 tok x 48] = Y[16x128] @ HW[128x48]
  f32x4 acch[3];
  #pragma unroll
  for (int n2 = 0; n2 < 3; ++n2){ acch[n2][0]=0.f; acch[n2][1]=0.f; acch[n2][2]=0.f; acch[n2][3]=0.f; }
  short8 A2[4];
  #pragma unroll
  for (int c = 0; c < 4; ++c)
    A2[c] = *(const short8*)&sY[r*136 + c*32 + q*8];
  #pragma unroll
  for (int c = 0; c < 4; ++c){
    #pragma unroll
    for (int n2 = 0; n2 < 3; ++n2)
      acch[n2] = __builtin_amdgcn_mfma_f32_16x16x32_bf16(A2[c], HBf[n2][c], acch[n2], 0, 0, 0);
  }
  #pragma unroll
  for (int n2 = 0; n2 < 3; ++n2){
    int col = n2*16 + r;
    if (col < NVOC){
      #pragma unroll
      for (int reg = 0; reg < 4; ++reg){
        int tok = base + q*4 + reg;
        out[tok*NVOC + col] = acch[n2][reg] + hb[n2];
      }
    }
  }
}

extern "C" void kernel_launch(void* const* d_in, const int* in_sizes, int n_in,
                              void* d_out, int out_size, void* d_ws, size_t ws_size,
                              hipStream_t stream){
  const int*   ids    = (const int*)  d_in[0];
  const float* emb    = (const float*)d_in[1];
  const float* w1     = (const float*)d_in[2];
  const float* b1     = (const float*)d_in[3];
  const float* w2     = (const float*)d_in[4];
  const float* b2     = (const float*)d_in[5];
  const float* wv_w   = (const float*)d_in[6];
  const float* wv_b   = (const float*)d_in[7];
  const float* mg_w   = (const float*)d_in[8];
  const float* mg_b   = (const float*)d_in[9];
  const float* ln_g   = (const float*)d_in[10];
  const float* ln_b   = (const float*)d_in[11];
  const float* head_w = (const float*)d_in[12];
  const float* head_b = (const float*)d_in[13];
  float* ws  = (float*)d_ws;
  float* out = (float*)d_out;
  k_pre1<<<dim3(127), dim3(128), 0, stream>>>(emb, w1, b1, wv_w, wv_b, mg_w, mg_b, ws);
  k_pre2<<<dim3(85),  dim3(128), 0, stream>>>(w2, b2, mg_w, ws);
  k_pre3<<<dim3(72),  dim3(256), 0, stream>>>(head_w, ws);
  k_main<<<dim3(512), dim3(256), 0, stream>>>(ids, ln_g, ln_b, head_b, ws, out);
}